// Round 4
// baseline (5048.562 us; speedup 1.0000x reference)
//
#include <hip/hip_runtime.h>
#include <hip/hip_bf16.h>
#include <hip/hip_fp16.h>

// Problem constants
#define BB   128
#define TT   256
#define EE   300
#define KP0  320             // E padded to mult of 64
#define HH   512
#define GG   2048            // 4*H gates
#define NC   11
#define MM   (BB*TT)         // 32768
#define START_TAG 9
#define STOP_TAG  10
#define NEGV (-100000.0f)

typedef _Float16 h2_t __attribute__((ext_vector_type(2)));
typedef _Float16 h4_t __attribute__((ext_vector_type(4)));
typedef _Float16 h8_t __attribute__((ext_vector_type(8)));
typedef float    f4_t __attribute__((ext_vector_type(4)));

// Fast transcendentals (v_exp + v_rcp). Safe here: h/gx are quantized to f16
// (5e-4) every step, so the <=1e-6 rel error of rcp/exp adds nothing.
__device__ __forceinline__ float sigf(float x) {
    return __builtin_amdgcn_rcpf(1.0f + __expf(-x));
}
__device__ __forceinline__ float tanh_fast(float x) {
    // tanh(x) = 1 - 2/(e^{2x}+1); saturates correctly at +-1, NaN-free
    float e = __expf(2.0f * x);
    return 1.0f - 2.0f * __builtin_amdgcn_rcpf(e + 1.0f);
}

// compile-safe global_load_lds wrapper: integer-cast detour (low 32 bits of a
// generic LDS pointer are the group-segment offset; AS1 is 64-bit flat).
__device__ __forceinline__ void gload_lds16(const void* g, void* l) {
    __builtin_amdgcn_global_load_lds(
        (const __attribute__((address_space(1))) void*)(unsigned long long)(uintptr_t)g,
        (__attribute__((address_space(3))) void*)(unsigned int)(uintptr_t)l,
        16, 0, 0);
}

// ---------------- fused prep: init (flags+loss) + 4 weight convert/pads ----------------
// Segments (256-thr blocks): [0,640) w_ih_l0, [640,1280) w_ih_l0r,
// [1280,3328) w_ih_l1, [3328,5376) w_ih_l1r. Block 0 also zeroes flags+loss.
__global__ __launch_bounds__(256) void prep_kernel(float* out, int* flags,
                                                   const float* __restrict__ wi0,  _Float16* __restrict__ o0,
                                                   const float* __restrict__ wi0r, _Float16* __restrict__ o0r,
                                                   const float* __restrict__ wi1,  _Float16* __restrict__ o1,
                                                   const float* __restrict__ wi1r, _Float16* __restrict__ o1r) {
    const int b = blockIdx.x, tid = threadIdx.x;
    if (b == 0) {
        if (tid == 0) out[MM] = 0.0f;
        for (int i = tid; i < 1024; i += 256) flags[i] = 0;
    }
    const float* src; _Float16* dst; int K, Kp4, base;
    if (b < 640)       { src = wi0;  dst = o0;  K = EE;   Kp4 = 80;  base = 0; }
    else if (b < 1280) { src = wi0r; dst = o0r; K = EE;   Kp4 = 80;  base = 640; }
    else if (b < 3328) { src = wi1;  dst = o1;  K = 1024; Kp4 = 256; base = 1280; }
    else               { src = wi1r; dst = o1r; K = 1024; Kp4 = 256; base = 3328; }
    int idx = (b - base) * 256 + tid;
    int r = idx / Kp4, c4 = idx % Kp4, c = c4 * 4;
    h4_t v;
    if (c < K) {
        float4 f = *(const float4*)(src + (size_t)r * K + c);
        v[0] = (_Float16)f.x; v[1] = (_Float16)f.y; v[2] = (_Float16)f.z; v[3] = (_Float16)f.w;
    } else {
        v[0] = v[1] = v[2] = v[3] = (_Float16)0.0f;
    }
    *(h4_t*)(dst + (size_t)r * (Kp4 * 4) + c) = v;
}

// ---------------- embedding gather -> f16 padded ----------------
__global__ __launch_bounds__(256) void embed16_kernel(const int* __restrict__ tok,
                                                      const float* __restrict__ emb,
                                                      _Float16* __restrict__ x0,
                                                      int total4) {
    int idx = blockIdx.x * 256 + threadIdx.x;
    if (idx >= total4) return;
    int m = idx / (KP0 / 4), c4 = idx % (KP0 / 4), c = c4 * 4;
    h4_t v;
    if (c < EE) {
        float4 f = *(const float4*)(emb + (size_t)tok[m] * EE + c);
        v[0] = (_Float16)f.x; v[1] = (_Float16)f.y; v[2] = (_Float16)f.z; v[3] = (_Float16)f.w;
    } else {
        v[0] = v[1] = v[2] = v[3] = (_Float16)0.0f;
    }
    *(h4_t*)(x0 + (size_t)m * KP0 + c) = v;
}

// ---------------- MFMA GEMM: C[m,n] = sum_k A[m,k]*W[n,k] + b1[n]+b2[n] ----------------
// m97 structure: global_load_lds width-16 staging into LINEAR [128][64] LDS.
__global__ __launch_bounds__(256) void gemm_bt_kernel(const _Float16* __restrict__ A,
                                                      const _Float16* __restrict__ Wf,
                                                      const float* __restrict__ b1,
                                                      const float* __restrict__ b2,
                                                      _Float16* __restrict__ C,
                                                      int Kp) {
    __shared__ __align__(16) char smem[36864];
    _Float16* As = (_Float16*)smem;             // [128][64] linear
    _Float16* Bs = (_Float16*)(smem + 16384);   // [128][64] linear
    const int tid = threadIdx.x;
    const int m0 = blockIdx.y * 128, n0 = blockIdx.x * 128;
    const int wv = tid >> 6, lane = tid & 63;
    const int wm = wv & 1, wn = wv >> 1;
    const int col = lane & 15, quad = lane >> 4;
    const int rb = lane >> 3;          // row within 8-row slab
    const int cb = (lane & 7) * 8;     // f16 col offset (16B per lane)

    f4_t acc[4][4];
#pragma unroll
    for (int i = 0; i < 4; ++i)
#pragma unroll
        for (int j = 0; j < 4; ++j) acc[i][j] = (f4_t){0.f, 0.f, 0.f, 0.f};

    for (int k0 = 0; k0 < Kp; k0 += 64) {
#pragma unroll
        for (int c = 0; c < 4; ++c) {
            int slab = c * 32 + wv * 8;            // wave-uniform 8-row slab
            gload_lds16(A  + (size_t)(m0 + slab + rb) * Kp + k0 + cb, As + slab * 64);
            gload_lds16(Wf + (size_t)(n0 + slab + rb) * Kp + k0 + cb, Bs + slab * 64);
        }
        __syncthreads();
#pragma unroll
        for (int kk = 0; kk < 2; ++kk) {
            h8_t af[4], bf[4];
#pragma unroll
            for (int i = 0; i < 4; ++i) {
                af[i] = *(const h8_t*)(As + (wm * 64 + i * 16 + col) * 64 + kk * 32 + quad * 8);
                bf[i] = *(const h8_t*)(Bs + (wn * 64 + i * 16 + col) * 64 + kk * 32 + quad * 8);
            }
#pragma unroll
            for (int mi = 0; mi < 4; ++mi)
#pragma unroll
                for (int ni = 0; ni < 4; ++ni)
                    acc[mi][ni] = __builtin_amdgcn_mfma_f32_16x16x32_f16(af[mi], bf[ni], acc[mi][ni], 0, 0, 0);
        }
        __syncthreads();
    }

    _Float16* Ct = (_Float16*)smem;   // [128][136]
#pragma unroll
    for (int ni = 0; ni < 4; ++ni) {
        int n = n0 + wn * 64 + ni * 16 + col;
        float bias = b1[n] + b2[n];
#pragma unroll
        for (int mi = 0; mi < 4; ++mi) {
#pragma unroll
            for (int r = 0; r < 4; ++r) {
                int mrow = wm * 64 + mi * 16 + quad * 4 + r;
                Ct[mrow * 136 + wn * 64 + ni * 16 + col] = (_Float16)(acc[mi][ni][r] + bias);
            }
        }
    }
    __syncthreads();
    {
        int row = tid >> 1, half = tid & 1;
#pragma unroll
        for (int cc2 = 0; cc2 < 8; ++cc2) {
            h8_t v = *(const h8_t*)(Ct + row * 136 + half * 64 + cc2 * 8);
            *(h8_t*)(C + (size_t)(m0 + row) * GG + n0 + half * 64 + cc2 * 8) = v;
        }
    }
}

// ============ weight-stationary persistent LSTM recurrence (fence-free) ============
// Grid: 2*nbg*16 WGs, 256 thr. 64KB LDS = W_hh slice + 1KB h-stage.
// h exchanged via MALL write-through (sc0 sc1) global ops; per-WG epoch flags.
// Proven protocol. This round's only change: tighter poll policy (first 8 polls
// back-to-back -- cadence is already rate-limited by the ~700cy MALL load --
// then short sleeps). Loads/stores/ordering byte-identical.
__global__ __launch_bounds__(256, 1) void lstm_rec3_kernel(
        const _Float16* __restrict__ gx_f, const _Float16* __restrict__ gx_r,
        const float* __restrict__ whh_f, const float* __restrict__ whh_r,
        const int* __restrict__ seqlen, int c0, int nbg,
        _Float16* __restrict__ hs, _Float16* __restrict__ hbuf, int* __restrict__ flags) {
    extern __shared__ _Float16 Wlds[];                 // 64KB W + 1KB stage
    _Float16* hstage = Wlds + 32768;                   // [32][16]

    const int wg = blockIdx.x;
    const int gs = wg & 15;
    const int grp = wg >> 4;
    const int bg = grp % nbg;
    const int dir = grp / nbg;
    const _Float16* gx = dir ? gx_r : gx_f;
    const float* W = dir ? whh_r : whh_f;
    int* myFlags = flags + grp * 16;
    _Float16* hb = hbuf + (size_t)grp * 2 * 16384;

    const int tid = threadIdx.x;
    const int wv = tid >> 6, lane = tid & 63;
    const int mt = wv & 1;
    const int p  = wv >> 1;
    const int col = lane & 15, quad = lane >> 4;

    // ---- pack W slice into LDS (one-time) ----
    for (int e = tid; e < 4096; e += 256) {
        int ln = e & 63, kc = (e >> 6) & 15, nt = e >> 10;
        int pp = nt >> 1;
        int n_in_pair = ((nt & 1) << 4) + (ln & 15);
        int gt = n_in_pair >> 3, jj = n_in_pair & 7;
        int R = gt * 512 + gs * 16 + pp * 8 + jj;
        int k = kc * 32 + (ln >> 4) * 8;
        const float4* src = (const float4*)(W + (size_t)R * 512 + k);
        float4 f0 = src[0], f1 = src[1];
        h8_t v;
        v[0] = (_Float16)f0.x; v[1] = (_Float16)f0.y; v[2] = (_Float16)f0.z; v[3] = (_Float16)f0.w;
        v[4] = (_Float16)f1.x; v[5] = (_Float16)f1.y; v[6] = (_Float16)f1.z; v[7] = (_Float16)f1.w;
        *(h8_t*)(Wlds + (size_t)e * 8) = v;
    }
    __syncthreads();

    // ---- hoist step-invariant B fragments LDS -> VGPRs (one-time) ----
    h8_t Bf0[16], Bf1[16];
#pragma unroll
    for (int kc = 0; kc < 16; ++kc) {
        Bf0[kc] = *(const h8_t*)(Wlds + (((p * 2 + 0) * 16 + kc) * 64 + lane) * 8);
        Bf1[kc] = *(const h8_t*)(Wlds + (((p * 2 + 1) * 16 + kc) * 64 + lane) * 8);
    }

    const int maxsl = seqlen[c0 + bg * 32];
    int sl_r[4];
#pragma unroll
    for (int r = 0; r < 4; ++r) sl_r[r] = seqlen[c0 + bg * 32 + mt * 16 + quad * 4 + r];

    const int jglob = gs * 16 + p * 8 + (col & 7);
    const int hi = col >> 3;

    // ---- prefetch gx for step 0 ----
    _Float16 pg0[4], pg1[4];
#pragma unroll
    for (int r = 0; r < 4; ++r) {
        pg0[r] = (_Float16)0.0f; pg1[r] = (_Float16)0.0f;
        if (0 < sl_r[r]) {
            int tm = dir ? (sl_r[r] - 1) : 0;
            int b_loc = bg * 32 + mt * 16 + quad * 4 + r;
            size_t base = ((size_t)(b_loc * TT + tm)) * GG;
            pg0[r] = gx[base + hi * 512 + jglob];
            pg1[r] = gx[base + 1024 + hi * 512 + jglob];
        }
    }

    // ---- publish h_{-1} = 0 into buf1 (wave0 only, write-through) ----
    if (tid < 64) {
        int m = tid >> 1, half = tid & 1;
        h8_t z = {};
        const _Float16* dst = hb + 16384 + m * 512 + gs * 16 + half * 8;
        asm volatile("global_store_dwordx4 %0, %1, off sc0 sc1" :: "v"(dst), "v"(z) : "memory");
        asm volatile("s_waitcnt vmcnt(0)" ::: "memory");
        if (tid == 0) {
            int one = 1;
            asm volatile("global_store_dword %0, %1, off sc0 sc1" :: "v"(myFlags + gs), "v"(one) : "memory");
        }
    }

    float cst[4] = {0.f, 0.f, 0.f, 0.f};
    float hst[4] = {0.f, 0.f, 0.f, 0.f};

    for (int s = 0; s < maxsl; ++s) {
        // ---- wait: all 16 WGs published h_{s-1} (tight poll, late backoff) ----
        if (tid < 16) {
            const int* fp = myFlags + tid;
            int v, it = 0;
            for (;;) {
                asm volatile("global_load_dword %0, %1, off sc0 sc1\n\ts_waitcnt vmcnt(0)"
                             : "=v"(v) : "v"(fp) : "memory");
                if (v >= s + 1) break;
                if (it >= 8) __builtin_amdgcn_s_sleep(2);
                ++it;
            }
        }
        __syncthreads();

        const _Float16* hrd = hb + ((s + 1) & 1) * 16384;
        _Float16* hwr = hb + (s & 1) * 16384;

        // ---- load A fragments (16 x dwordx4, MALL-bypass, one drain) ----
        h8_t a[16];
        const _Float16* ap = hrd + (mt * 16 + col) * 512 + quad * 8;
#pragma unroll
        for (int kc = 0; kc < 16; ++kc)
            asm volatile("global_load_dwordx4 %0, %1, off sc0 sc1"
                         : "=v"(a[kc]) : "v"(ap + kc * 32));
        asm volatile("s_waitcnt vmcnt(0)" ::: "memory");
        __builtin_amdgcn_sched_barrier(0);   // rule 18: keep MFMAs after the drain

        // ---- MFMA with register-resident B; 2-way split dep chains ----
        f4_t acc0a = {0.f, 0.f, 0.f, 0.f}, acc0b = {0.f, 0.f, 0.f, 0.f};
        f4_t acc1a = {0.f, 0.f, 0.f, 0.f}, acc1b = {0.f, 0.f, 0.f, 0.f};
#pragma unroll
        for (int kc = 0; kc < 8; ++kc) {
            acc0a = __builtin_amdgcn_mfma_f32_16x16x32_f16(a[kc], Bf0[kc], acc0a, 0, 0, 0);
            acc1a = __builtin_amdgcn_mfma_f32_16x16x32_f16(a[kc], Bf1[kc], acc1a, 0, 0, 0);
        }
#pragma unroll
        for (int kc = 8; kc < 16; ++kc) {
            acc0b = __builtin_amdgcn_mfma_f32_16x16x32_f16(a[kc], Bf0[kc], acc0b, 0, 0, 0);
            acc1b = __builtin_amdgcn_mfma_f32_16x16x32_f16(a[kc], Bf1[kc], acc1b, 0, 0, 0);
        }
        f4_t acc0 = acc0a + acc0b;
        f4_t acc1 = acc1a + acc1b;

        // ---- gates + state update (gx already in regs); stage h in LDS ----
#pragma unroll
        for (int r = 0; r < 4; ++r) {
            const bool valid = (s < sl_r[r]);
            float a0 = acc0[r] + (float)pg0[r];
            float a1 = acc1[r] + (float)pg1[r];
            float x0v = __shfl_xor(a0, 8);
            float x1v = __shfl_xor(a1, 8);
            float gi = hi ? x0v : a0;
            float gf = hi ? a0 : x0v;
            float gg2 = hi ? x1v : a1;
            float go = hi ? a1 : x1v;
            if (valid) {
                float cn = sigf(gf) * cst[r] + sigf(gi) * tanh_fast(gg2);
                cst[r] = cn;
                hst[r] = sigf(go) * tanh_fast(cn);
            }
            if (!hi)
                hstage[(mt * 16 + quad * 4 + r) * 16 + p * 8 + (col & 7)] = (_Float16)hst[r];
        }
        __syncthreads();

        // ---- wave0-only publish of h_s; flag follows in-wave after drain ----
        if (tid < 64) {
            int m = tid >> 1, half = tid & 1;
            h8_t v = *(const h8_t*)(hstage + m * 16 + half * 8);
            const _Float16* dst = hwr + m * 512 + gs * 16 + half * 8;
            asm volatile("global_store_dwordx4 %0, %1, off sc0 sc1" :: "v"(dst), "v"(v) : "memory");
            asm volatile("s_waitcnt vmcnt(0)" ::: "memory");
            if (tid == 0) {
                int fv = s + 2;
                asm volatile("global_store_dword %0, %1, off sc0 sc1" :: "v"(myFlags + gs), "v"(fv) : "memory");
            }
        }

        // ---- post-flag shadow work: overlaps the next step's poll ----
        // hs output stores (plain, fire-and-forget)
#pragma unroll
        for (int r = 0; r < 4; ++r) {
            const bool valid = (s < sl_r[r]);
            if (valid && !hi) {
                int b_loc = bg * 32 + mt * 16 + quad * 4 + r;
                int tm = dir ? (sl_r[r] - 1 - s) : s;
                hs[((size_t)(b_loc * TT + tm) << 10) + (dir << 9) + jglob] = (_Float16)hst[r];
            }
        }
        // gx prefetch for step s+1 (HBM latency hides under next poll)
        {
            int sn = s + 1;
#pragma unroll
            for (int r = 0; r < 4; ++r) {
                pg0[r] = (_Float16)0.0f; pg1[r] = (_Float16)0.0f;
                if (sn < sl_r[r]) {
                    int tm = dir ? (sl_r[r] - 1 - sn) : sn;
                    int b_loc = bg * 32 + mt * 16 + quad * 4 + r;
                    size_t base = ((size_t)(b_loc * TT + tm)) * GG;
                    pg0[r] = gx[base + hi * 512 + jglob];
                    pg1[r] = gx[base + 1024 + hi * 512 + jglob];
                }
            }
        }
    }
}

// ---------------- emissions: one wave per hs-row, fc_w staged in LDS ----------------
// hs read ONCE, coalesced (64 lanes x 16 f16 = full 1024-f16 row in 2 loads).
// Per lane: 11 f32 dot-partials against LDS fc_w; 6-round shfl_down tree; lane 0
// stores the 11 outputs. WG = 4 waves x 4 rows = 16 rows.
__global__ __launch_bounds__(256) void emis_kernel(const _Float16* __restrict__ hs,
                                                   const float* __restrict__ fc_w,
                                                   const float* __restrict__ fc_b,
                                                   float* __restrict__ emis, int Mc) {
    __shared__ __align__(16) float Wl[NC * 1024];   // 45056 B
    __shared__ float fb[NC];
    const int tid = threadIdx.x;
    {
        const float4* s4 = (const float4*)fc_w;
        float4* d4 = (float4*)Wl;
        for (int i = tid; i < NC * 256; i += 256) d4[i] = s4[i];
        if (tid < NC) fb[tid] = fc_b[tid];
    }
    __syncthreads();
    const int wv = tid >> 6, lane = tid & 63;

    for (int i = 0; i < 4; ++i) {
        int m = blockIdx.x * 16 + wv * 4 + i;
        if (m >= Mc) return;
        const h8_t* xp = (const h8_t*)(hs + (size_t)m * 1024);
        h8_t xa = xp[lane * 2], xb = xp[lane * 2 + 1];
        float xf[16];
#pragma unroll
        for (int j = 0; j < 8; ++j) { xf[j] = (float)xa[j]; xf[8 + j] = (float)xb[j]; }

        float s[NC];
#pragma unroll
        for (int c = 0; c < NC; ++c) {
            const float4* wr = (const float4*)(Wl + c * 1024 + lane * 16);
            float4 w0 = wr[0], w1 = wr[1], w2 = wr[2], w3 = wr[3];
            s[c] = xf[0] * w0.x + xf[1] * w0.y + xf[2] * w0.z + xf[3] * w0.w
                 + xf[4] * w1.x + xf[5] * w1.y + xf[6] * w1.z + xf[7] * w1.w
                 + xf[8] * w2.x + xf[9] * w2.y + xf[10] * w2.z + xf[11] * w2.w
                 + xf[12] * w3.x + xf[13] * w3.y + xf[14] * w3.z + xf[15] * w3.w;
        }
#pragma unroll
        for (int off = 32; off > 0; off >>= 1)
#pragma unroll
            for (int c = 0; c < NC; ++c) s[c] += __shfl_down(s[c], off);
        if (lane == 0) {
            float* eo = emis + (size_t)m * NC;
#pragma unroll
            for (int c = 0; c < NC; ++c) eo[c] = s[c] + fb[c];
        }
    }
}

// ---------------- CRF: Viterbi + NLL forward ----------------
// Backtrack table kept in LDS (2816 B) -- kills the 256 serial dependent global
// loads of the old backtrack. emis row loads software-pipelined (prefetch t+1).
__global__ __launch_bounds__(64) void crf_kernel(const float* __restrict__ emis,
                                                 const int* __restrict__ seq_len,
                                                 const int* __restrict__ tags,
                                                 const float* __restrict__ trans,
                                                 float* __restrict__ out, int c0) {
    const int b_loc = blockIdx.x;
    const int b = c0 + b_loc;
    const int lane = threadIdx.x;
    __shared__ float tr[NC * NC];
    __shared__ unsigned char btl[TT * NC];   // 2816 B backtrack table
    for (int i = lane; i < NC * NC; i += 64) tr[i] = trans[i];
    __syncthreads();
    const int sl = seq_len[b];
    const bool act = lane < NC;
    const int jj = act ? lane : 0;

    float vs = 0.0f;
    float ns = NEGV;

    float ej_cur = act ? emis[(size_t)(b_loc * TT) * NC + lane] : 0.0f;
    for (int t = 0; t < sl; ++t) {
        float ej_next = (act && t + 1 < sl) ? emis[(size_t)(b_loc * TT + t + 1) * NC + lane] : 0.0f;
        float vmax = -1e30f, nmax = -1e30f;
        int varg = 0;
        float nsave[NC];
#pragma unroll
        for (int i = 0; i < NC; ++i) {
            float vi = __shfl(vs, i);
            float ni = __shfl(ns, i);
            float tij = tr[i * NC + jj];
            float cv = vi + tij;
            if (cv > vmax) { vmax = cv; varg = i; }
            float cn = ni + tij;
            nsave[i] = cn;
            if (cn > nmax) nmax = cn;
        }
        float ssum = 0.f;
#pragma unroll
        for (int i = 0; i < NC; ++i) ssum += expf(nsave[i] - nmax);
        if (act) {
            vs = vmax + ej_cur;
            ns = nmax + logf(ssum) + ej_cur;
            btl[t * NC + lane] = (unsigned char)varg;
        }
        ej_cur = ej_next;
    }

    float finv = act ? vs + tr[lane * NC + STOP_TAG] : -1e30f;
    float finn = act ? ns + tr[lane * NC + STOP_TAG] : -1e30f;
    float vbest = -1e30f, fmax = -1e30f;
    int barg = 0;
#pragma unroll
    for (int j = 0; j < NC; ++j) {
        float v = __shfl(finv, j);
        if (v > vbest) { vbest = v; barg = j; }
        float n = __shfl(finn, j);
        if (n > fmax) fmax = n;
    }
    float fsum = 0.f;
#pragma unroll
    for (int j = 0; j < NC; ++j) fsum += expf(__shfl(finn, j) - fmax);
    float fwd = fmax + logf(fsum);

    float gsum = 0.f;
    for (int t = lane; t < sl; t += 64) {
        int tg = tags[b * TT + t];
        int pv = (t == 0) ? START_TAG : tags[b * TT + t - 1];
        gsum += emis[(size_t)(b_loc * TT + t) * NC + tg] + tr[pv * NC + tg];
    }
#pragma unroll
    for (int off = 32; off > 0; off >>= 1) gsum += __shfl_down(gsum, off);

    if (lane == 0) {
        float gold = gsum + tr[tags[b * TT + sl - 1] * NC + STOP_TAG];
        atomicAdd(out + MM, (fwd - gold) * (1.0f / (float)BB));
        int cur = barg;
        for (int l = sl - 1; l >= 0; --l) {
            out[b * TT + l] = (float)cur;
            if (l >= 1) cur = (int)btl[l * NC + cur];
        }
    }
    for (int l = sl + lane; l < TT; l += 64) out[b * TT + l] = 0.0f;
}

// ---------------- launch ----------------
extern "C" void kernel_launch(void* const* d_in, const int* in_sizes, int n_in,
                              void* d_out, int out_size, void* d_ws, size_t ws_size,
                              hipStream_t stream) {
    (void)in_sizes; (void)n_in; (void)out_size;
    const int* tokens = (const int*)d_in[0];
    const int* seqlen = (const int*)d_in[1];
    const int* tags = (const int*)d_in[3];
    const float* emb = (const float*)d_in[4];
    const float* w_ih_l0  = (const float*)d_in[5];
    const float* w_hh_l0  = (const float*)d_in[6];
    const float* b_ih_l0  = (const float*)d_in[7];
    const float* b_hh_l0  = (const float*)d_in[8];
    const float* w_ih_l0r = (const float*)d_in[9];
    const float* w_hh_l0r = (const float*)d_in[10];
    const float* b_ih_l0r = (const float*)d_in[11];
    const float* b_hh_l0r = (const float*)d_in[12];
    const float* w_ih_l1  = (const float*)d_in[13];
    const float* w_hh_l1  = (const float*)d_in[14];
    const float* b_ih_l1  = (const float*)d_in[15];
    const float* b_hh_l1  = (const float*)d_in[16];
    const float* w_ih_l1r = (const float*)d_in[17];
    const float* w_hh_l1r = (const float*)d_in[18];
    const float* b_ih_l1r = (const float*)d_in[19];
    const float* b_hh_l1r = (const float*)d_in[20];
    const float* fc_w  = (const float*)d_in[21];
    const float* fc_b  = (const float*)d_in[22];
    const float* trans = (const float*)d_in[23];

    // ---- workspace layout ----
    const size_t per_b = 2097152u + 524288u + 163840u + 11264u + 2816u;  // 2,799,360
    const size_t fixed = 524288u + 4096u + 2u * 1310720u + 2u * 4194304u;
    int Bc = 128;
    while (Bc > 32 && fixed + per_b * (size_t)Bc > ws_size) Bc >>= 1;

    char* ws = (char*)d_ws;
    _Float16* hbuf = (_Float16*)ws;               // 8 grp x 2 x 32x512 f16
    int* flags = (int*)(ws + 524288u);            // 1024 ints
    _Float16* w0f = (_Float16*)(ws + 528384u);
    _Float16* w0r = (_Float16*)(ws + 528384u + 1310720u);
    _Float16* w1f = (_Float16*)(ws + 528384u + 2u * 1310720u);
    _Float16* w1r = (_Float16*)(ws + 528384u + 2u * 1310720u + 4194304u);
    char* p = ws + fixed;
    _Float16* gxf   = (_Float16*)p;   p += (size_t)Bc * 1048576u;
    _Float16* gxr   = (_Float16*)p;   p += (size_t)Bc * 1048576u;
    _Float16* hs    = (_Float16*)p;   p += (size_t)Bc * 524288u;
    _Float16* x0f16 = (_Float16*)p;   p += (size_t)Bc * 163840u;
    float* emis     = (float*)p;      p += (size_t)Bc * 11264u;
    float* out = (float*)d_out;   // pred as floats [0,MM), loss at [MM]

    prep_kernel<<<5376, 256, 0, stream>>>(out, flags,
                                          w_ih_l0, w0f, w_ih_l0r, w0r,
                                          w_ih_l1, w1f, w_ih_l1r, w1r);

    const int nbg = Bc / 32;
    const int nchunk = BB / Bc;
    for (int cidx = 0; cidx < nchunk; ++cidx) {
        const int c0 = cidx * Bc;
        const int Mc = Bc * TT;
        dim3 gdim(GG / 128, Mc / 128);
        int* fl_l0 = flags + (cidx * 2 + 0) * 128;
        int* fl_l1 = flags + (cidx * 2 + 1) * 128;

        embed16_kernel<<<(Mc * 80 + 255) / 256, 256, 0, stream>>>(tokens + c0 * TT, emb, x0f16, Mc * 80);
        gemm_bt_kernel<<<gdim, 256, 0, stream>>>(x0f16, w0f, b_ih_l0,  b_hh_l0,  gxf, KP0);
        gemm_bt_kernel<<<gdim, 256, 0, stream>>>(x0f16, w0r, b_ih_l0r, b_hh_l0r, gxr, KP0);
        lstm_rec3_kernel<<<2 * nbg * 16, 256, 66560, stream>>>(
            gxf, gxr, w_hh_l0, w_hh_l0r, seqlen, c0, nbg, hs, hbuf, fl_l0);
        gemm_bt_kernel<<<gdim, 256, 0, stream>>>(hs, w1f, b_ih_l1,  b_hh_l1,  gxf, 1024);
        gemm_bt_kernel<<<gdim, 256, 0, stream>>>(hs, w1r, b_ih_l1r, b_hh_l1r, gxr, 1024);
        lstm_rec3_kernel<<<2 * nbg * 16, 256, 66560, stream>>>(
            gxf, gxr, w_hh_l1, w_hh_l1r, seqlen, c0, nbg, hs, hbuf, fl_l1);
        emis_kernel<<<Mc / 16, 256, 0, stream>>>(hs, fc_w, fc_b, emis, Mc);
        crf_kernel<<<Bc, 64, 0, stream>>>(emis, seqlen, tags, trans, out, c0);
    }
}

// Round 5
// 4828.406 us; speedup vs baseline: 1.0456x; 1.0456x over previous
//
#include <hip/hip_runtime.h>
#include <hip/hip_bf16.h>
#include <hip/hip_fp16.h>

// Problem constants
#define BB   128
#define TT   256
#define EE   300
#define KP0  320             // E padded to mult of 64
#define HH   512
#define GG   2048            // 4*H gates
#define NC   11
#define MM   (BB*TT)         // 32768
#define START_TAG 9
#define STOP_TAG  10
#define NEGV (-100000.0f)

typedef _Float16 h2_t __attribute__((ext_vector_type(2)));
typedef _Float16 h4_t __attribute__((ext_vector_type(4)));
typedef _Float16 h8_t __attribute__((ext_vector_type(8)));
typedef float    f4_t __attribute__((ext_vector_type(4)));

// Fast transcendentals (v_exp + v_rcp). Safe here: h/gx are quantized to f16
// (5e-4) every step, so the <=1e-6 rel error of rcp/exp adds nothing.
__device__ __forceinline__ float sigf(float x) {
    return __builtin_amdgcn_rcpf(1.0f + __expf(-x));
}
__device__ __forceinline__ float tanh_fast(float x) {
    // tanh(x) = 1 - 2/(e^{2x}+1); saturates correctly at +-1, NaN-free
    float e = __expf(2.0f * x);
    return 1.0f - 2.0f * __builtin_amdgcn_rcpf(e + 1.0f);
}

// compile-safe global_load_lds wrapper: integer-cast detour (low 32 bits of a
// generic LDS pointer are the group-segment offset; AS1 is 64-bit flat).
__device__ __forceinline__ void gload_lds16(const void* g, void* l) {
    __builtin_amdgcn_global_load_lds(
        (const __attribute__((address_space(1))) void*)(unsigned long long)(uintptr_t)g,
        (__attribute__((address_space(3))) void*)(unsigned int)(uintptr_t)l,
        16, 0, 0);
}

// ---------------- fused prep: init (flags+loss) + 4 weight convert/pads ----------------
__global__ __launch_bounds__(256) void prep_kernel(float* out, int* flags,
                                                   const float* __restrict__ wi0,  _Float16* __restrict__ o0,
                                                   const float* __restrict__ wi0r, _Float16* __restrict__ o0r,
                                                   const float* __restrict__ wi1,  _Float16* __restrict__ o1,
                                                   const float* __restrict__ wi1r, _Float16* __restrict__ o1r) {
    const int b = blockIdx.x, tid = threadIdx.x;
    if (b == 0) {
        if (tid == 0) out[MM] = 0.0f;
        for (int i = tid; i < 1024; i += 256) flags[i] = 0;
    }
    const float* src; _Float16* dst; int K, Kp4, base;
    if (b < 640)       { src = wi0;  dst = o0;  K = EE;   Kp4 = 80;  base = 0; }
    else if (b < 1280) { src = wi0r; dst = o0r; K = EE;   Kp4 = 80;  base = 640; }
    else if (b < 3328) { src = wi1;  dst = o1;  K = 1024; Kp4 = 256; base = 1280; }
    else               { src = wi1r; dst = o1r; K = 1024; Kp4 = 256; base = 3328; }
    int idx = (b - base) * 256 + tid;
    int r = idx / Kp4, c4 = idx % Kp4, c = c4 * 4;
    h4_t v;
    if (c < K) {
        float4 f = *(const float4*)(src + (size_t)r * K + c);
        v[0] = (_Float16)f.x; v[1] = (_Float16)f.y; v[2] = (_Float16)f.z; v[3] = (_Float16)f.w;
    } else {
        v[0] = v[1] = v[2] = v[3] = (_Float16)0.0f;
    }
    *(h4_t*)(dst + (size_t)r * (Kp4 * 4) + c) = v;
}

// ---------------- embedding gather -> f16 padded ----------------
__global__ __launch_bounds__(256) void embed16_kernel(const int* __restrict__ tok,
                                                      const float* __restrict__ emb,
                                                      _Float16* __restrict__ x0,
                                                      int total4) {
    int idx = blockIdx.x * 256 + threadIdx.x;
    if (idx >= total4) return;
    int m = idx / (KP0 / 4), c4 = idx % (KP0 / 4), c = c4 * 4;
    h4_t v;
    if (c < EE) {
        float4 f = *(const float4*)(emb + (size_t)tok[m] * EE + c);
        v[0] = (_Float16)f.x; v[1] = (_Float16)f.y; v[2] = (_Float16)f.z; v[3] = (_Float16)f.w;
    } else {
        v[0] = v[1] = v[2] = v[3] = (_Float16)0.0f;
    }
    *(h4_t*)(x0 + (size_t)m * KP0 + c) = v;
}

// ---------------- MFMA GEMM: C[m,n] = sum_k A[m,k]*W[n,k] + b1[n]+b2[n] ----------------
// Double-buffered 2-phase DMA pipeline (T3/T4-minimal) + both-sides XOR swizzle
// (T2, rule 21): DMA dest linear, per-lane GLOBAL source column pre-swizzled
// (cb ^ (rb<<3)), ds_read applies the same XOR -> conflict-free b128 reads.
// Counted s_waitcnt vmcnt(8) keeps next tile's 8 DMAs in flight across the
// barrier; only the last iter drains to 0.
__global__ __launch_bounds__(256) void gemm_bt_kernel(const _Float16* __restrict__ A,
                                                      const _Float16* __restrict__ Wf,
                                                      const float* __restrict__ b1,
                                                      const float* __restrict__ b2,
                                                      _Float16* __restrict__ C,
                                                      int Kp) {
    __shared__ __align__(16) char smem[65536];
    _Float16* As0 = (_Float16*)smem;              // [128][64] linear
    _Float16* Bs0 = (_Float16*)(smem + 16384);
    _Float16* As1 = (_Float16*)(smem + 32768);
    _Float16* Bs1 = (_Float16*)(smem + 49152);
    const int tid = threadIdx.x;
    const int m0 = blockIdx.y * 128, n0 = blockIdx.x * 128;
    const int wv = tid >> 6, lane = tid & 63;
    const int wm = wv & 1, wn = wv >> 1;
    const int col = lane & 15, quad = lane >> 4;
    const int rb = lane >> 3;                     // row within 8-row slab
    const int cbs = ((lane & 7) * 8) ^ (rb << 3); // pre-swizzled source col (f16)
    const int rsw = (lane & 7) * 8;               // read-side XOR (f16)

    f4_t acc[4][4];
#pragma unroll
    for (int i = 0; i < 4; ++i)
#pragma unroll
        for (int j = 0; j < 4; ++j) acc[i][j] = (f4_t){0.f, 0.f, 0.f, 0.f};

#define STAGE(Ad, Bd, kk0)                                                              \
    _Pragma("unroll")                                                                   \
    for (int c = 0; c < 4; ++c) {                                                       \
        int slab = c * 32 + wv * 8;                                                     \
        gload_lds16(A  + (size_t)(m0 + slab + rb) * Kp + (kk0) + cbs, (Ad) + slab * 64);\
        gload_lds16(Wf + (size_t)(n0 + slab + rb) * Kp + (kk0) + cbs, (Bd) + slab * 64);\
    }

    const int nt = Kp >> 6;
    STAGE(As0, Bs0, 0);                           // prologue: tile 0 in flight (8 DMAs)

    for (int t = 0; t < nt; ++t) {
        const _Float16* Ac = (t & 1) ? As1 : As0;
        const _Float16* Bc = (t & 1) ? Bs1 : Bs0;
        if (t + 1 < nt) {
            _Float16* An = (t & 1) ? As0 : As1;
            _Float16* Bn = (t & 1) ? Bs0 : Bs1;
            STAGE(An, Bn, (t + 1) * 64);          // 8 DMAs for next tile
            asm volatile("s_waitcnt vmcnt(8)" ::: "memory");   // cur's 8 done, next's in flight
        } else {
            asm volatile("s_waitcnt vmcnt(0)" ::: "memory");   // epilogue drain
        }
        __builtin_amdgcn_s_barrier();             // all waves' cur-DMAs landed
        __builtin_amdgcn_sched_barrier(0);        // rule 18: no hoisting above barrier

#pragma unroll
        for (int kk = 0; kk < 2; ++kk) {
            h8_t af[4], bf[4];
#pragma unroll
            for (int i = 0; i < 4; ++i) {
                af[i] = *(const h8_t*)(Ac + (wm * 64 + i * 16 + col) * 64 + ((kk * 32 + quad * 8) ^ rsw));
                bf[i] = *(const h8_t*)(Bc + (wn * 64 + i * 16 + col) * 64 + ((kk * 32 + quad * 8) ^ rsw));
            }
#pragma unroll
            for (int mi = 0; mi < 4; ++mi)
#pragma unroll
                for (int ni = 0; ni < 4; ++ni)
                    acc[mi][ni] = __builtin_amdgcn_mfma_f32_16x16x32_f16(af[mi], bf[ni], acc[mi][ni], 0, 0, 0);
        }
        __builtin_amdgcn_sched_barrier(0);        // keep reads before the close barrier
        __builtin_amdgcn_s_barrier();             // reads of cur done before overwrite
    }
#undef STAGE

    _Float16* Ct = (_Float16*)smem;   // [128][136]
#pragma unroll
    for (int ni = 0; ni < 4; ++ni) {
        int n = n0 + wn * 64 + ni * 16 + col;
        float bias = b1[n] + b2[n];
#pragma unroll
        for (int mi = 0; mi < 4; ++mi) {
#pragma unroll
            for (int r = 0; r < 4; ++r) {
                int mrow = wm * 64 + mi * 16 + quad * 4 + r;
                Ct[mrow * 136 + wn * 64 + ni * 16 + col] = (_Float16)(acc[mi][ni][r] + bias);
            }
        }
    }
    __syncthreads();
    {
        int row = tid >> 1, half = tid & 1;
#pragma unroll
        for (int cc2 = 0; cc2 < 8; ++cc2) {
            h8_t v = *(const h8_t*)(Ct + row * 136 + half * 64 + cc2 * 8);
            *(h8_t*)(C + (size_t)(m0 + row) * GG + n0 + half * 64 + cc2 * 8) = v;
        }
    }
}

// ============ weight-stationary persistent LSTM recurrence (fence-free) ============
// Grid: 2*nbg*16 WGs, 256 thr. 64KB LDS = W_hh slice + 1KB h-stage.
// h exchanged via MALL write-through (sc0 sc1) global ops; per-WG epoch flags.
// Proven protocol; poll policy = round-3 backoff (best measured).
__global__ __launch_bounds__(256, 1) void lstm_rec3_kernel(
        const _Float16* __restrict__ gx_f, const _Float16* __restrict__ gx_r,
        const float* __restrict__ whh_f, const float* __restrict__ whh_r,
        const int* __restrict__ seqlen, int c0, int nbg,
        _Float16* __restrict__ hs, _Float16* __restrict__ hbuf, int* __restrict__ flags) {
    extern __shared__ _Float16 Wlds[];                 // 64KB W + 1KB stage
    _Float16* hstage = Wlds + 32768;                   // [32][16]

    const int wg = blockIdx.x;
    const int gs = wg & 15;
    const int grp = wg >> 4;
    const int bg = grp % nbg;
    const int dir = grp / nbg;
    const _Float16* gx = dir ? gx_r : gx_f;
    const float* W = dir ? whh_r : whh_f;
    int* myFlags = flags + grp * 16;
    _Float16* hb = hbuf + (size_t)grp * 2 * 16384;

    const int tid = threadIdx.x;
    const int wv = tid >> 6, lane = tid & 63;
    const int mt = wv & 1;
    const int p  = wv >> 1;
    const int col = lane & 15, quad = lane >> 4;

    // ---- pack W slice into LDS (one-time) ----
    for (int e = tid; e < 4096; e += 256) {
        int ln = e & 63, kc = (e >> 6) & 15, nt = e >> 10;
        int pp = nt >> 1;
        int n_in_pair = ((nt & 1) << 4) + (ln & 15);
        int gt = n_in_pair >> 3, jj = n_in_pair & 7;
        int R = gt * 512 + gs * 16 + pp * 8 + jj;
        int k = kc * 32 + (ln >> 4) * 8;
        const float4* src = (const float4*)(W + (size_t)R * 512 + k);
        float4 f0 = src[0], f1 = src[1];
        h8_t v;
        v[0] = (_Float16)f0.x; v[1] = (_Float16)f0.y; v[2] = (_Float16)f0.z; v[3] = (_Float16)f0.w;
        v[4] = (_Float16)f1.x; v[5] = (_Float16)f1.y; v[6] = (_Float16)f1.z; v[7] = (_Float16)f1.w;
        *(h8_t*)(Wlds + (size_t)e * 8) = v;
    }
    __syncthreads();

    // ---- hoist step-invariant B fragments LDS -> VGPRs (one-time) ----
    h8_t Bf0[16], Bf1[16];
#pragma unroll
    for (int kc = 0; kc < 16; ++kc) {
        Bf0[kc] = *(const h8_t*)(Wlds + (((p * 2 + 0) * 16 + kc) * 64 + lane) * 8);
        Bf1[kc] = *(const h8_t*)(Wlds + (((p * 2 + 1) * 16 + kc) * 64 + lane) * 8);
    }

    const int maxsl = seqlen[c0 + bg * 32];
    int sl_r[4];
#pragma unroll
    for (int r = 0; r < 4; ++r) sl_r[r] = seqlen[c0 + bg * 32 + mt * 16 + quad * 4 + r];

    const int jglob = gs * 16 + p * 8 + (col & 7);
    const int hi = col >> 3;

    // ---- prefetch gx for step 0 ----
    _Float16 pg0[4], pg1[4];
#pragma unroll
    for (int r = 0; r < 4; ++r) {
        pg0[r] = (_Float16)0.0f; pg1[r] = (_Float16)0.0f;
        if (0 < sl_r[r]) {
            int tm = dir ? (sl_r[r] - 1) : 0;
            int b_loc = bg * 32 + mt * 16 + quad * 4 + r;
            size_t base = ((size_t)(b_loc * TT + tm)) * GG;
            pg0[r] = gx[base + hi * 512 + jglob];
            pg1[r] = gx[base + 1024 + hi * 512 + jglob];
        }
    }

    // ---- publish h_{-1} = 0 into buf1 (wave0 only, write-through) ----
    if (tid < 64) {
        int m = tid >> 1, half = tid & 1;
        h8_t z = {};
        const _Float16* dst = hb + 16384 + m * 512 + gs * 16 + half * 8;
        asm volatile("global_store_dwordx4 %0, %1, off sc0 sc1" :: "v"(dst), "v"(z) : "memory");
        asm volatile("s_waitcnt vmcnt(0)" ::: "memory");
        if (tid == 0) {
            int one = 1;
            asm volatile("global_store_dword %0, %1, off sc0 sc1" :: "v"(myFlags + gs), "v"(one) : "memory");
        }
    }

    float cst[4] = {0.f, 0.f, 0.f, 0.f};
    float hst[4] = {0.f, 0.f, 0.f, 0.f};

    for (int s = 0; s < maxsl; ++s) {
        // ---- wait: all 16 WGs published h_{s-1} (progressive backoff) ----
        if (tid < 16) {
            const int* fp = myFlags + tid;
            int v, it = 0;
            for (;;) {
                asm volatile("global_load_dword %0, %1, off sc0 sc1\n\ts_waitcnt vmcnt(0)"
                             : "=v"(v) : "v"(fp) : "memory");
                if (v >= s + 1) break;
                if (it < 3) __builtin_amdgcn_s_sleep(1);
                else        __builtin_amdgcn_s_sleep(4);
                ++it;
            }
        }
        __syncthreads();

        const _Float16* hrd = hb + ((s + 1) & 1) * 16384;
        _Float16* hwr = hb + (s & 1) * 16384;

        // ---- load A fragments (16 x dwordx4, MALL-bypass, one drain) ----
        h8_t a[16];
        const _Float16* ap = hrd + (mt * 16 + col) * 512 + quad * 8;
#pragma unroll
        for (int kc = 0; kc < 16; ++kc)
            asm volatile("global_load_dwordx4 %0, %1, off sc0 sc1"
                         : "=v"(a[kc]) : "v"(ap + kc * 32));
        asm volatile("s_waitcnt vmcnt(0)" ::: "memory");
        __builtin_amdgcn_sched_barrier(0);   // rule 18: keep MFMAs after the drain

        // ---- MFMA with register-resident B; 2-way split dep chains ----
        f4_t acc0a = {0.f, 0.f, 0.f, 0.f}, acc0b = {0.f, 0.f, 0.f, 0.f};
        f4_t acc1a = {0.f, 0.f, 0.f, 0.f}, acc1b = {0.f, 0.f, 0.f, 0.f};
#pragma unroll
        for (int kc = 0; kc < 8; ++kc) {
            acc0a = __builtin_amdgcn_mfma_f32_16x16x32_f16(a[kc], Bf0[kc], acc0a, 0, 0, 0);
            acc1a = __builtin_amdgcn_mfma_f32_16x16x32_f16(a[kc], Bf1[kc], acc1a, 0, 0, 0);
        }
#pragma unroll
        for (int kc = 8; kc < 16; ++kc) {
            acc0b = __builtin_amdgcn_mfma_f32_16x16x32_f16(a[kc], Bf0[kc], acc0b, 0, 0, 0);
            acc1b = __builtin_amdgcn_mfma_f32_16x16x32_f16(a[kc], Bf1[kc], acc1b, 0, 0, 0);
        }
        f4_t acc0 = acc0a + acc0b;
        f4_t acc1 = acc1a + acc1b;

        // ---- gates + state update (gx already in regs); stage h in LDS ----
#pragma unroll
        for (int r = 0; r < 4; ++r) {
            const bool valid = (s < sl_r[r]);
            float a0 = acc0[r] + (float)pg0[r];
            float a1 = acc1[r] + (float)pg1[r];
            float x0v = __shfl_xor(a0, 8);
            float x1v = __shfl_xor(a1, 8);
            float gi = hi ? x0v : a0;
            float gf = hi ? a0 : x0v;
            float gg2 = hi ? x1v : a1;
            float go = hi ? a1 : x1v;
            if (valid) {
                float cn = sigf(gf) * cst[r] + sigf(gi) * tanh_fast(gg2);
                cst[r] = cn;
                hst[r] = sigf(go) * tanh_fast(cn);
            }
            if (!hi)
                hstage[(mt * 16 + quad * 4 + r) * 16 + p * 8 + (col & 7)] = (_Float16)hst[r];
        }
        __syncthreads();

        // ---- wave0-only publish of h_s; flag follows in-wave after drain ----
        if (tid < 64) {
            int m = tid >> 1, half = tid & 1;
            h8_t v = *(const h8_t*)(hstage + m * 16 + half * 8);
            const _Float16* dst = hwr + m * 512 + gs * 16 + half * 8;
            asm volatile("global_store_dwordx4 %0, %1, off sc0 sc1" :: "v"(dst), "v"(v) : "memory");
            asm volatile("s_waitcnt vmcnt(0)" ::: "memory");
            if (tid == 0) {
                int fv = s + 2;
                asm volatile("global_store_dword %0, %1, off sc0 sc1" :: "v"(myFlags + gs), "v"(fv) : "memory");
            }
        }

        // ---- post-flag shadow work: overlaps the next step's poll ----
        // hs output stores (plain, fire-and-forget)
#pragma unroll
        for (int r = 0; r < 4; ++r) {
            const bool valid = (s < sl_r[r]);
            if (valid && !hi) {
                int b_loc = bg * 32 + mt * 16 + quad * 4 + r;
                int tm = dir ? (sl_r[r] - 1 - s) : s;
                hs[((size_t)(b_loc * TT + tm) << 10) + (dir << 9) + jglob] = (_Float16)hst[r];
            }
        }
        // gx prefetch for step s+1 (HBM latency hides under next poll)
        {
            int sn = s + 1;
#pragma unroll
            for (int r = 0; r < 4; ++r) {
                pg0[r] = (_Float16)0.0f; pg1[r] = (_Float16)0.0f;
                if (sn < sl_r[r]) {
                    int tm = dir ? (sl_r[r] - 1 - sn) : sn;
                    int b_loc = bg * 32 + mt * 16 + quad * 4 + r;
                    size_t base = ((size_t)(b_loc * TT + tm)) * GG;
                    pg0[r] = gx[base + hi * 512 + jglob];
                    pg1[r] = gx[base + 1024 + hi * 512 + jglob];
                }
            }
        }
    }
}

// ---------------- emissions: one wave per hs-row, fc_w staged in LDS ----------------
__global__ __launch_bounds__(256) void emis_kernel(const _Float16* __restrict__ hs,
                                                   const float* __restrict__ fc_w,
                                                   const float* __restrict__ fc_b,
                                                   float* __restrict__ emis, int Mc) {
    __shared__ __align__(16) float Wl[NC * 1024];   // 45056 B
    __shared__ float fb[NC];
    const int tid = threadIdx.x;
    {
        const float4* s4 = (const float4*)fc_w;
        float4* d4 = (float4*)Wl;
        for (int i = tid; i < NC * 256; i += 256) d4[i] = s4[i];
        if (tid < NC) fb[tid] = fc_b[tid];
    }
    __syncthreads();
    const int wv = tid >> 6, lane = tid & 63;

    for (int i = 0; i < 4; ++i) {
        int m = blockIdx.x * 16 + wv * 4 + i;
        if (m >= Mc) return;
        const h8_t* xp = (const h8_t*)(hs + (size_t)m * 1024);
        h8_t xa = xp[lane * 2], xb = xp[lane * 2 + 1];
        float xf[16];
#pragma unroll
        for (int j = 0; j < 8; ++j) { xf[j] = (float)xa[j]; xf[8 + j] = (float)xb[j]; }

        float s[NC];
#pragma unroll
        for (int c = 0; c < NC; ++c) {
            const float4* wr = (const float4*)(Wl + c * 1024 + lane * 16);
            float4 w0 = wr[0], w1 = wr[1], w2 = wr[2], w3 = wr[3];
            s[c] = xf[0] * w0.x + xf[1] * w0.y + xf[2] * w0.z + xf[3] * w0.w
                 + xf[4] * w1.x + xf[5] * w1.y + xf[6] * w1.z + xf[7] * w1.w
                 + xf[8] * w2.x + xf[9] * w2.y + xf[10] * w2.z + xf[11] * w2.w
                 + xf[12] * w3.x + xf[13] * w3.y + xf[14] * w3.z + xf[15] * w3.w;
        }
#pragma unroll
        for (int off = 32; off > 0; off >>= 1)
#pragma unroll
            for (int c = 0; c < NC; ++c) s[c] += __shfl_down(s[c], off);
        if (lane == 0) {
            float* eo = emis + (size_t)m * NC;
#pragma unroll
            for (int c = 0; c < NC; ++c) eo[c] = s[c] + fb[c];
        }
    }
}

// ---------------- CRF: Viterbi + NLL forward ----------------
__global__ __launch_bounds__(64) void crf_kernel(const float* __restrict__ emis,
                                                 const int* __restrict__ seq_len,
                                                 const int* __restrict__ tags,
                                                 const float* __restrict__ trans,
                                                 float* __restrict__ out, int c0) {
    const int b_loc = blockIdx.x;
    const int b = c0 + b_loc;
    const int lane = threadIdx.x;
    __shared__ float tr[NC * NC];
    __shared__ unsigned char btl[TT * NC];   // 2816 B backtrack table
    for (int i = lane; i < NC * NC; i += 64) tr[i] = trans[i];
    __syncthreads();
    const int sl = seq_len[b];
    const bool act = lane < NC;
    const int jj = act ? lane : 0;

    float vs = 0.0f;
    float ns = NEGV;

    float ej_cur = act ? emis[(size_t)(b_loc * TT) * NC + lane] : 0.0f;
    for (int t = 0; t < sl; ++t) {
        float ej_next = (act && t + 1 < sl) ? emis[(size_t)(b_loc * TT + t + 1) * NC + lane] : 0.0f;
        float vmax = -1e30f, nmax = -1e30f;
        int varg = 0;
        float nsave[NC];
#pragma unroll
        for (int i = 0; i < NC; ++i) {
            float vi = __shfl(vs, i);
            float ni = __shfl(ns, i);
            float tij = tr[i * NC + jj];
            float cv = vi + tij;
            if (cv > vmax) { vmax = cv; varg = i; }
            float cn = ni + tij;
            nsave[i] = cn;
            if (cn > nmax) nmax = cn;
        }
        float ssum = 0.f;
#pragma unroll
        for (int i = 0; i < NC; ++i) ssum += expf(nsave[i] - nmax);
        if (act) {
            vs = vmax + ej_cur;
            ns = nmax + logf(ssum) + ej_cur;
            btl[t * NC + lane] = (unsigned char)varg;
        }
        ej_cur = ej_next;
    }

    float finv = act ? vs + tr[lane * NC + STOP_TAG] : -1e30f;
    float finn = act ? ns + tr[lane * NC + STOP_TAG] : -1e30f;
    float vbest = -1e30f, fmax = -1e30f;
    int barg = 0;
#pragma unroll
    for (int j = 0; j < NC; ++j) {
        float v = __shfl(finv, j);
        if (v > vbest) { vbest = v; barg = j; }
        float n = __shfl(finn, j);
        if (n > fmax) fmax = n;
    }
    float fsum = 0.f;
#pragma unroll
    for (int j = 0; j < NC; ++j) fsum += expf(__shfl(finn, j) - fmax);
    float fwd = fmax + logf(fsum);

    float gsum = 0.f;
    for (int t = lane; t < sl; t += 64) {
        int tg = tags[b * TT + t];
        int pv = (t == 0) ? START_TAG : tags[b * TT + t - 1];
        gsum += emis[(size_t)(b_loc * TT + t) * NC + tg] + tr[pv * NC + tg];
    }
#pragma unroll
    for (int off = 32; off > 0; off >>= 1) gsum += __shfl_down(gsum, off);

    if (lane == 0) {
        float gold = gsum + tr[tags[b * TT + sl - 1] * NC + STOP_TAG];
        atomicAdd(out + MM, (fwd - gold) * (1.0f / (float)BB));
        int cur = barg;
        for (int l = sl - 1; l >= 0; --l) {
            out[b * TT + l] = (float)cur;
            if (l >= 1) cur = (int)btl[l * NC + cur];
        }
    }
    for (int l = sl + lane; l < TT; l += 64) out[b * TT + l] = 0.0f;
}

// ---------------- launch ----------------
extern "C" void kernel_launch(void* const* d_in, const int* in_sizes, int n_in,
                              void* d_out, int out_size, void* d_ws, size_t ws_size,
                              hipStream_t stream) {
    (void)in_sizes; (void)n_in; (void)out_size;
    const int* tokens = (const int*)d_in[0];
    const int* seqlen = (const int*)d_in[1];
    const int* tags = (const int*)d_in[3];
    const float* emb = (const float*)d_in[4];
    const float* w_ih_l0  = (const float*)d_in[5];
    const float* w_hh_l0  = (const float*)d_in[6];
    const float* b_ih_l0  = (const float*)d_in[7];
    const float* b_hh_l0  = (const float*)d_in[8];
    const float* w_ih_l0r = (const float*)d_in[9];
    const float* w_hh_l0r = (const float*)d_in[10];
    const float* b_ih_l0r = (const float*)d_in[11];
    const float* b_hh_l0r = (const float*)d_in[12];
    const float* w_ih_l1  = (const float*)d_in[13];
    const float* w_hh_l1  = (const float*)d_in[14];
    const float* b_ih_l1  = (const float*)d_in[15];
    const float* b_hh_l1  = (const float*)d_in[16];
    const float* w_ih_l1r = (const float*)d_in[17];
    const float* w_hh_l1r = (const float*)d_in[18];
    const float* b_ih_l1r = (const float*)d_in[19];
    const float* b_hh_l1r = (const float*)d_in[20];
    const float* fc_w  = (const float*)d_in[21];
    const float* fc_b  = (const float*)d_in[22];
    const float* trans = (const float*)d_in[23];

    // ---- workspace layout ----
    const size_t per_b = 2097152u + 524288u + 163840u + 11264u + 2816u;  // 2,799,360
    const size_t fixed = 524288u + 4096u + 2u * 1310720u + 2u * 4194304u;
    int Bc = 128;
    while (Bc > 32 && fixed + per_b * (size_t)Bc > ws_size) Bc >>= 1;

    char* ws = (char*)d_ws;
    _Float16* hbuf = (_Float16*)ws;               // 8 grp x 2 x 32x512 f16
    int* flags = (int*)(ws + 524288u);            // 1024 ints
    _Float16* w0f = (_Float16*)(ws + 528384u);
    _Float16* w0r = (_Float16*)(ws + 528384u + 1310720u);
    _Float16* w1f = (_Float16*)(ws + 528384u + 2u * 1310720u);
    _Float16* w1r = (_Float16*)(ws + 528384u + 2u * 1310720u + 4194304u);
    char* p = ws + fixed;
    _Float16* gxf   = (_Float16*)p;   p += (size_t)Bc * 1048576u;
    _Float16* gxr   = (_Float16*)p;   p += (size_t)Bc * 1048576u;
    _Float16* hs    = (_Float16*)p;   p += (size_t)Bc * 524288u;
    _Float16* x0f16 = (_Float16*)p;   p += (size_t)Bc * 163840u;
    float* emis     = (float*)p;      p += (size_t)Bc * 11264u;
    float* out = (float*)d_out;   // pred as floats [0,MM), loss at [MM]

    prep_kernel<<<5376, 256, 0, stream>>>(out, flags,
                                          w_ih_l0, w0f, w_ih_l0r, w0r,
                                          w_ih_l1, w1f, w_ih_l1r, w1r);

    const int nbg = Bc / 32;
    const int nchunk = BB / Bc;
    for (int cidx = 0; cidx < nchunk; ++cidx) {
        const int c0 = cidx * Bc;
        const int Mc = Bc * TT;
        dim3 gdim(GG / 128, Mc / 128);
        int* fl_l0 = flags + (cidx * 2 + 0) * 128;
        int* fl_l1 = flags + (cidx * 2 + 1) * 128;

        embed16_kernel<<<(Mc * 80 + 255) / 256, 256, 0, stream>>>(tokens + c0 * TT, emb, x0f16, Mc * 80);
        gemm_bt_kernel<<<gdim, 256, 0, stream>>>(x0f16, w0f, b_ih_l0,  b_hh_l0,  gxf, KP0);
        gemm_bt_kernel<<<gdim, 256, 0, stream>>>(x0f16, w0r, b_ih_l0r, b_hh_l0r, gxr, KP0);
        lstm_rec3_kernel<<<2 * nbg * 16, 256, 66560, stream>>>(
            gxf, gxr, w_hh_l0, w_hh_l0r, seqlen, c0, nbg, hs, hbuf, fl_l0);
        gemm_bt_kernel<<<gdim, 256, 0, stream>>>(hs, w1f, b_ih_l1,  b_hh_l1,  gxf, 1024);
        gemm_bt_kernel<<<gdim, 256, 0, stream>>>(hs, w1r, b_ih_l1r, b_hh_l1r, gxr, 1024);
        lstm_rec3_kernel<<<2 * nbg * 16, 256, 66560, stream>>>(
            gxf, gxr, w_hh_l1, w_hh_l1r, seqlen, c0, nbg, hs, hbuf, fl_l1);
        emis_kernel<<<Mc / 16, 256, 0, stream>>>(hs, fc_w, fc_b, emis, Mc);
        crf_kernel<<<Bc, 64, 0, stream>>>(emis, seqlen, tags, trans, out, c0);
    }
}